// Round 4
// baseline (1494.814 us; speedup 1.0000x reference)
//
#include <hip/hip_runtime.h>
#include <cstdint>
#include <cstddef>

#define N_INS    16384
#define INS_DIM  2048
#define N_CLS    81
#define BANK     10
#define UCAP     512

// ---------------------------------------------------------------------------
// Kernel 1: per-class mean over bank + ||mean||^2 (f64)
// ---------------------------------------------------------------------------
__global__ __launch_bounds__(256)
void prep_kernel(const float* __restrict__ memory,
                 float*  __restrict__ mean_out,   // [81][2048]
                 double* __restrict__ base_out)   // [81]
{
    const int c = blockIdx.x;
    const int t = threadIdx.x;
    double nrm = 0.0;
    #pragma unroll
    for (int rep = 0; rep < 2; ++rep) {
        const int d4 = (t + rep * 256) * 4;
        float sx = 0.f, sy = 0.f, sz = 0.f, sw = 0.f;
        #pragma unroll
        for (int b = 0; b < BANK; ++b) {
            const float4 v = *(const float4*)(memory + ((size_t)(c * BANK + b)) * INS_DIM + d4);
            sx += v.x; sy += v.y; sz += v.z; sw += v.w;
        }
        sx /= 10.0f; sy /= 10.0f; sz /= 10.0f; sw /= 10.0f;
        *(float4*)(mean_out + (size_t)c * INS_DIM + d4) = make_float4(sx, sy, sz, sw);
        nrm += (double)sx * sx + (double)sy * sy + (double)sz * sz + (double)sw * sw;
    }
    #pragma unroll
    for (int o = 32; o >= 1; o >>= 1) nrm += __shfl_xor(nrm, o, 64);
    __shared__ double sred[4];
    const int w = t >> 6, lane = t & 63;
    if (lane == 0) sred[w] = nrm;
    __syncthreads();
    if (t == 0) base_out[c] = sred[0] + sred[1] + sred[2] + sred[3];
}

// ---------------------------------------------------------------------------
// Kernel 2: classification GEMM. Grid 512 = 256 M-tiles x 2 N-halves.
// Block 256 thr: kh = t>>6 (4-way k split), mg = (t>>3)&7 (8 inst), ng = t&7
// (6 classes). Tile M=64 x N=48 x BK=32. All LDS frag reads are b128 with
// XOR-swizzled k-chunks (conflict-free). Dbuf, one barrier per ktile.
// ---------------------------------------------------------------------------
struct TileMem { float a[2][64 * 32]; float b[2][48 * 32]; };
union CSMem {
    TileMem t;                                   // 28 KB
    double  red[64 * 48];                        // 24.6 KB
    struct { double fs[64 * 8]; int fc[64 * 8]; } fin;
};

__global__ __launch_bounds__(256, 2)
void classify_kernel(const float* __restrict__ instances,
                     const float* __restrict__ mean_in,   // [81][2048]
                     const double* __restrict__ base_in,  // [81]
                     double* __restrict__ bestS,          // [2][16384]
                     int*    __restrict__ bestC)          // [2][16384]
{
    __shared__ CSMem sm;

    const int t  = threadIdx.x;
    const int ng = t & 7;
    const int mg = (t >> 3) & 7;
    const int kh = t >> 6;
    const int i0 = (blockIdx.x >> 1) * 64;
    const int nh = blockIdx.x & 1;

    // staging maps (A: 2 chunks/thread of 512; B: 1 or 2 of 384)
    const int caA0 = t, caA1 = t + 256;
    const float* pA0 = instances + (size_t)(i0 + (caA0 >> 3)) * INS_DIM + (caA0 & 7) * 4;
    const float* pA1 = instances + (size_t)(i0 + (caA1 >> 3)) * INS_DIM + (caA1 & 7) * 4;
    const int dA0 = (caA0 >> 3) * 32 + (((caA0 & 7) ^ ((caA0 >> 6) & 7)) * 4);
    const int dA1 = (caA1 >> 3) * 32 + (((caA1 & 7) ^ ((caA1 >> 6) & 7)) * 4);
    const int cbB0 = t;
    const int rB0  = nh * 48 + (cbB0 >> 3);
    const float* pB0 = mean_in + (size_t)((rB0 < N_CLS) ? rB0 : (N_CLS - 1)) * INS_DIM + (cbB0 & 7) * 4;
    const int dB0 = (cbB0 >> 3) * 32 + (((cbB0 & 7) ^ ((cbB0 >> 6) & 7)) * 4);
    const bool hasB1 = (t < 128);
    const int cbB1 = 256 + t;
    const int rB1  = nh * 48 + (cbB1 >> 3);
    const float* pB1 = mean_in + (size_t)((rB1 < N_CLS) ? rB1 : (N_CLS - 1)) * INS_DIM + (cbB1 & 7) * 4;
    const int dB1 = (cbB1 >> 3) * 32 + (((cbB1 & 7) ^ ((cbB1 >> 6) & 7)) * 4);

    float  cacc[8][6];
    double dacc[8][6];
    #pragma unroll
    for (int q = 0; q < 8; ++q)
        #pragma unroll
        for (int j = 0; j < 6; ++j) { cacc[q][j] = 0.f; dacc[q][j] = 0.0; }

    float4 gA0 = *(const float4*)pA0;
    float4 gA1 = *(const float4*)pA1;
    float4 gB0 = *(const float4*)pB0;
    float4 gB1 = hasB1 ? *(const float4*)pB1 : make_float4(0, 0, 0, 0);

    for (int kt = 0; kt < 64; ++kt) {
        const int pb = kt & 1;
        *(float4*)&sm.t.a[pb][dA0] = gA0;
        *(float4*)&sm.t.a[pb][dA1] = gA1;
        *(float4*)&sm.t.b[pb][dB0] = gB0;
        if (hasB1) *(float4*)&sm.t.b[pb][dB1] = gB1;
        __syncthreads();
        if (kt < 63) {
            gA0 = *(const float4*)(pA0 + (size_t)(kt + 1) * 32);
            gA1 = *(const float4*)(pA1 + (size_t)(kt + 1) * 32);
            gB0 = *(const float4*)(pB0 + (size_t)(kt + 1) * 32);
            if (hasB1) gB1 = *(const float4*)(pB1 + (size_t)(kt + 1) * 32);
        }
        #pragma unroll
        for (int g = 0; g < 2; ++g) {
            const int cb = kh * 2 + g;   // k-chunk index (4 floats each)
            float4 av[8], bv[6];
            #pragma unroll
            for (int q = 0; q < 8; ++q)
                av[q] = *(const float4*)&sm.t.a[pb][(mg * 8 + q) * 32 + ((cb ^ mg) & 7) * 4];
            #pragma unroll
            for (int j = 0; j < 6; ++j) {
                const int row = ng * 6 + j;
                bv[j] = *(const float4*)&sm.t.b[pb][row * 32 + ((cb ^ ((row >> 3) & 7)) & 7) * 4];
            }
            #pragma unroll
            for (int q = 0; q < 8; ++q)
                #pragma unroll
                for (int j = 0; j < 6; ++j) {
                    cacc[q][j] = fmaf(av[q].x, bv[j].x, cacc[q][j]);
                    cacc[q][j] = fmaf(av[q].y, bv[j].y, cacc[q][j]);
                    cacc[q][j] = fmaf(av[q].z, bv[j].z, cacc[q][j]);
                    cacc[q][j] = fmaf(av[q].w, bv[j].w, cacc[q][j]);
                }
        }
        if (kt & 1) {
            #pragma unroll
            for (int q = 0; q < 8; ++q)
                #pragma unroll
                for (int j = 0; j < 6; ++j) { dacc[q][j] += (double)cacc[q][j]; cacc[q][j] = 0.f; }
        }
    }

    // combine the 4 kh partials (f64) via LDS, 3 phases
    __syncthreads();
    const int r = t & 63;
    for (int ph = 1; ph <= 3; ++ph) {
        if (kh == ph) {
            #pragma unroll
            for (int q = 0; q < 8; ++q)
                #pragma unroll
                for (int j = 0; j < 6; ++j) sm.red[r * 48 + q * 6 + j] = dacc[q][j];
        }
        __syncthreads();
        if (kh == 0) {
            #pragma unroll
            for (int q = 0; q < 8; ++q)
                #pragma unroll
                for (int j = 0; j < 6; ++j) dacc[q][j] += sm.red[r * 48 + q * 6 + j];
        }
        __syncthreads();
    }

    if (kh == 0) {
        #pragma unroll
        for (int q = 0; q < 8; ++q) {
            double best = 1e300; int bc = 1 << 30;
            #pragma unroll
            for (int j = 0; j < 6; ++j) {
                const int cg = nh * 48 + ng * 6 + j;
                if (cg < N_CLS) {
                    const double sc = base_in[cg] - 2.0 * dacc[q][j];
                    if (sc < best) { best = sc; bc = cg; }
                }
            }
            sm.fin.fs[(mg * 8 + q) * 8 + ng] = best;
            sm.fin.fc[(mg * 8 + q) * 8 + ng] = bc;
        }
    }
    __syncthreads();
    if (t < 64) {
        double best = sm.fin.fs[t * 8]; int bc = sm.fin.fc[t * 8];
        #pragma unroll
        for (int gq = 1; gq < 8; ++gq) {
            const double v = sm.fin.fs[t * 8 + gq];
            if (v < best) { best = v; bc = sm.fin.fc[t * 8 + gq]; }
        }
        bestS[(size_t)nh * N_INS + i0 + t] = best;
        bestC[(size_t)nh * N_INS + i0 + t] = bc;
    }
}

// ---------------------------------------------------------------------------
// Kernel 2b: combine the two N-halves -> cls_out + acc
// ---------------------------------------------------------------------------
__global__ __launch_bounds__(256)
void combine_kernel(const double* __restrict__ bestS,
                    const int*    __restrict__ bestC,
                    const int*    __restrict__ labels,
                    float* __restrict__ cls_out,
                    float* __restrict__ acc_out)
{
    const int i = blockIdx.x * 256 + threadIdx.x;
    const double s0 = bestS[i];
    const double s1 = bestS[N_INS + i];
    const int    c0 = bestC[i];
    const int    c1 = bestC[N_INS + i];
    const int c = (s1 < s0) ? c1 : c0;   // tie -> lower class (half 0)
    cls_out[i] = (float)c;
    const unsigned long long mb = __ballot(c == labels[i]);
    if ((threadIdx.x & 63) == 0)
        atomicAdd(acc_out, (float)__popcll(mb) * (1.0f / 16384.0f));
}

// ---------------------------------------------------------------------------
// Kernel 3: sequential per-class update. ONE WAVE per class, zero barriers,
// bank register-resident (no lambdas -> no scratch demotion). One-step
// lookahead: during step i compute D'_s = m_s.x_{i+1}, c = x_i.x_{i+1},
// ||x_{i+1}||^2 (vs pre-decision bank); fix up next step with the single
// changed slot. Scores: argmax ||m_s-x||^2 == argmax (||m_s||^2 - 2 m_s.x).
// ---------------------------------------------------------------------------

#define DOT12(XCUR, XNXT, OUTA)                                                \
  do {                                                                         \
    _Pragma("unroll")                                                          \
    for (int s_ = 0; s_ < 10; ++s_) {                                          \
      float a0_ = 0.f, a1_ = 0.f;                                              \
      _Pragma("unroll")                                                        \
      for (int j_ = 0; j_ < 4; ++j_) {                                         \
        a0_ = fmaf(m[s_][j_].x, (XNXT)[j_].x, a0_);                            \
        a0_ = fmaf(m[s_][j_].y, (XNXT)[j_].y, a0_);                            \
        a0_ = fmaf(m[s_][j_].z, (XNXT)[j_].z, a0_);                            \
        a0_ = fmaf(m[s_][j_].w, (XNXT)[j_].w, a0_);                            \
      }                                                                        \
      _Pragma("unroll")                                                        \
      for (int j_ = 4; j_ < 8; ++j_) {                                         \
        a1_ = fmaf(m[s_][j_].x, (XNXT)[j_].x, a1_);                            \
        a1_ = fmaf(m[s_][j_].y, (XNXT)[j_].y, a1_);                            \
        a1_ = fmaf(m[s_][j_].z, (XNXT)[j_].z, a1_);                            \
        a1_ = fmaf(m[s_][j_].w, (XNXT)[j_].w, a1_);                            \
      }                                                                        \
      OUTA[s_] = (double)a0_ + (double)a1_;                                    \
    }                                                                          \
    { float a0_ = 0.f, a1_ = 0.f;                                              \
      _Pragma("unroll")                                                        \
      for (int j_ = 0; j_ < 4; ++j_) {                                         \
        a0_ = fmaf((XCUR)[j_].x, (XNXT)[j_].x, a0_);                           \
        a0_ = fmaf((XCUR)[j_].y, (XNXT)[j_].y, a0_);                           \
        a0_ = fmaf((XCUR)[j_].z, (XNXT)[j_].z, a0_);                           \
        a0_ = fmaf((XCUR)[j_].w, (XNXT)[j_].w, a0_);                           \
      }                                                                        \
      _Pragma("unroll")                                                        \
      for (int j_ = 4; j_ < 8; ++j_) {                                         \
        a1_ = fmaf((XCUR)[j_].x, (XNXT)[j_].x, a1_);                           \
        a1_ = fmaf((XCUR)[j_].y, (XNXT)[j_].y, a1_);                           \
        a1_ = fmaf((XCUR)[j_].z, (XNXT)[j_].z, a1_);                           \
        a1_ = fmaf((XCUR)[j_].w, (XNXT)[j_].w, a1_);                           \
      }                                                                        \
      OUTA[10] = (double)a0_ + (double)a1_; }                                  \
    { float a0_ = 0.f, a1_ = 0.f;                                              \
      _Pragma("unroll")                                                        \
      for (int j_ = 0; j_ < 4; ++j_) {                                         \
        a0_ = fmaf((XNXT)[j_].x, (XNXT)[j_].x, a0_);                           \
        a0_ = fmaf((XNXT)[j_].y, (XNXT)[j_].y, a0_);                           \
        a0_ = fmaf((XNXT)[j_].z, (XNXT)[j_].z, a0_);                           \
        a0_ = fmaf((XNXT)[j_].w, (XNXT)[j_].w, a0_);                           \
      }                                                                        \
      _Pragma("unroll")                                                        \
      for (int j_ = 4; j_ < 8; ++j_) {                                         \
        a1_ = fmaf((XNXT)[j_].x, (XNXT)[j_].x, a1_);                           \
        a1_ = fmaf((XNXT)[j_].y, (XNXT)[j_].y, a1_);                           \
        a1_ = fmaf((XNXT)[j_].z, (XNXT)[j_].z, a1_);                           \
        a1_ = fmaf((XNXT)[j_].w, (XNXT)[j_].w, a1_);                           \
      }                                                                        \
      OUTA[11] = (double)a0_ + (double)a1_; }                                  \
    _Pragma("unroll")                                                          \
    for (int o_ = 32; o_ >= 1; o_ >>= 1) {                                     \
      _Pragma("unroll")                                                        \
      for (int v_ = 0; v_ < 12; ++v_) OUTA[v_] += __shfl_xor(OUTA[v_], o_, 64);\
    }                                                                          \
  } while (0)

#define UPD_STEP(XC_, XD_, II_)                                                \
  do { if ((II_) < cnt) {                                                      \
    const int pfi_ = ((II_) + 2 < cnt) ? ((II_) + 2) : (cnt - 1);              \
    const int pf_  = s_list[pfi_];                                             \
    double nx_[12];                                                            \
    DOT12(XC_, XD_, nx_);                                                      \
    int widx_;                                                                 \
    if (p < BANK) {                                                            \
      widx_ = p;                                                               \
    } else {                                                                   \
      double bs_ = nrm[0] - 2.0 * ((0 == wprev) ? ccur : Dcur[0]);             \
      widx_ = 0;                                                               \
      _Pragma("unroll")                                                        \
      for (int s_ = 1; s_ < 10; ++s_) {                                        \
        const double v_ = nrm[s_] - 2.0 * ((s_ == wprev) ? ccur : Dcur[s_]);   \
        if (v_ > bs_) { bs_ = v_; widx_ = s_; }                                \
      }                                                                        \
    }                                                                          \
    const int sw_ = __builtin_amdgcn_readfirstlane(widx_);                     \
    _Pragma("unroll")                                                          \
    for (int s_ = 0; s_ < 10; ++s_) {                                          \
      if (sw_ == s_) {                                                         \
        _Pragma("unroll")                                                      \
        for (int j_ = 0; j_ < 8; ++j_) m[s_][j_] = (XC_)[j_];                  \
        nrm[s_] = xxcur;                                                       \
      }                                                                        \
    }                                                                          \
    if (p < BANK) ++p;                                                         \
    wprev = widx_;                                                             \
    { const float* pp_ = instances + (size_t)pf_ * INS_DIM + l * 4;            \
      _Pragma("unroll")                                                        \
      for (int j_ = 0; j_ < 8; ++j_) (XC_)[j_] = *(const float4*)(pp_ + j_ * 256); } \
    _Pragma("unroll")                                                          \
    for (int v_ = 0; v_ < 10; ++v_) Dcur[v_] = nx_[v_];                        \
    ccur = nx_[10]; xxcur = nx_[11];                                           \
  } } while (0)

__global__ __launch_bounds__(64, 1)
void update_kernel(const float* __restrict__ instances,
                   const int*   __restrict__ labels,
                   const float* __restrict__ memory,
                   const int*   __restrict__ memory_pos,
                   float* __restrict__ mem_out,   // [81][10][2048]
                   float* __restrict__ pos_out)   // [81]
{
    __shared__ int s_list[UCAP];

    const int c = blockIdx.x;
    const int l = threadIdx.x;
    const unsigned long long below = (1ull << l) - 1ull;

    // ---- Phase 1: stable compaction (pipelined batches of 8 x int4/lane)
    int cnt = 0;
    {
        int4 lb[2][8];
        #pragma unroll
        for (int u = 0; u < 8; ++u) lb[0][u] = ((const int4*)labels)[u * 64 + l];
        for (int bt = 0; bt < 8; ++bt) {
            const int cur = bt & 1;
            if (bt < 7) {
                #pragma unroll
                for (int u = 0; u < 8; ++u)
                    lb[cur ^ 1][u] = ((const int4*)labels)[((bt + 1) * 8 + u) * 64 + l];
            }
            #pragma unroll
            for (int u = 0; u < 8; ++u) {
                const int4 lv = lb[cur][u];
                const int base = (bt * 8 + u) * 256 + 4 * l;
                const bool q0 = (lv.x == c), q1 = (lv.y == c), q2 = (lv.z == c), q3 = (lv.w == c);
                const unsigned long long b0 = __ballot(q0), b1 = __ballot(q1),
                                         b2 = __ballot(q2), b3 = __ballot(q3);
                int pos = cnt + (int)(__popcll(b0 & below) + __popcll(b1 & below) +
                                      __popcll(b2 & below) + __popcll(b3 & below));
                if (q0) { if (pos < UCAP) s_list[pos] = base + 0; ++pos; }
                if (q1) { if (pos < UCAP) s_list[pos] = base + 1; ++pos; }
                if (q2) { if (pos < UCAP) s_list[pos] = base + 2; ++pos; }
                if (q3) { if (pos < UCAP) s_list[pos] = base + 3; ++pos; }
                cnt += (int)(__popcll(b0) + __popcll(b1) + __popcll(b2) + __popcll(b3));
            }
        }
        if (cnt > UCAP) cnt = UCAP;
    }

    // ---- Phase 2: bank -> registers; initial slot norms (f64, butterfly once)
    float4 m[BANK][8];
    #pragma unroll
    for (int s = 0; s < BANK; ++s)
        #pragma unroll
        for (int j = 0; j < 8; ++j)
            m[s][j] = *(const float4*)(memory + ((size_t)(c * BANK + s)) * INS_DIM + j * 256 + l * 4);

    double nrm[BANK];
    #pragma unroll
    for (int s = 0; s < BANK; ++s) {
        float a0 = 0.f, a1 = 0.f;
        #pragma unroll
        for (int j = 0; j < 4; ++j) {
            a0 = fmaf(m[s][j].x, m[s][j].x, a0); a0 = fmaf(m[s][j].y, m[s][j].y, a0);
            a0 = fmaf(m[s][j].z, m[s][j].z, a0); a0 = fmaf(m[s][j].w, m[s][j].w, a0);
        }
        #pragma unroll
        for (int j = 4; j < 8; ++j) {
            a1 = fmaf(m[s][j].x, m[s][j].x, a1); a1 = fmaf(m[s][j].y, m[s][j].y, a1);
            a1 = fmaf(m[s][j].z, m[s][j].z, a1); a1 = fmaf(m[s][j].w, m[s][j].w, a1);
        }
        nrm[s] = (double)a0 + (double)a1;
    }
    #pragma unroll
    for (int o = 32; o >= 1; o >>= 1)
        #pragma unroll
        for (int s = 0; s < BANK; ++s) nrm[s] += __shfl_xor(nrm[s], o, 64);

    int p = memory_pos[c];

    // ---- Phase 3: lookahead scan (no barriers)
    float4 xA[8], xB[8];
    double Dcur[10], ccur = 0.0, xxcur = 0.0;
    int wprev = -1;
    #pragma unroll
    for (int j = 0; j < 8; ++j) { xA[j] = make_float4(0, 0, 0, 0); xB[j] = make_float4(0, 0, 0, 0); }
    #pragma unroll
    for (int v = 0; v < 10; ++v) Dcur[v] = 0.0;

    if (cnt > 0) {
        const float* p0 = instances + (size_t)s_list[0] * INS_DIM + l * 4;
        #pragma unroll
        for (int j = 0; j < 8; ++j) xA[j] = *(const float4*)(p0 + j * 256);
        const float* p1 = instances + (size_t)s_list[(cnt > 1) ? 1 : 0] * INS_DIM + l * 4;
        #pragma unroll
        for (int j = 0; j < 8; ++j) xB[j] = *(const float4*)(p1 + j * 256);
        double pr_[12];
        DOT12(xA, xA, pr_);
        #pragma unroll
        for (int v = 0; v < 10; ++v) Dcur[v] = pr_[v];
        ccur = pr_[10]; xxcur = pr_[11];
    }

    int ii = 0;
    while (ii < cnt) {
        UPD_STEP(xA, xB, ii);
        UPD_STEP(xB, xA, ii + 1);
        ii += 2;
    }

    // ---- Phase 4: write bank + pos
    #pragma unroll
    for (int s = 0; s < BANK; ++s)
        #pragma unroll
        for (int j = 0; j < 8; ++j)
            *(float4*)(mem_out + ((size_t)(c * BANK + s)) * INS_DIM + j * 256 + l * 4) = m[s][j];
    if (l == 0) pos_out[c] = (float)p;
}

// ---------------------------------------------------------------------------
extern "C" void kernel_launch(void* const* d_in, const int* in_sizes, int n_in,
                              void* d_out, int out_size, void* d_ws, size_t ws_size,
                              hipStream_t stream)
{
    const float* instances = (const float*)d_in[0];
    const int*   labels    = (const int*)  d_in[1];
    const float* memory    = (const float*)d_in[2];
    const int*   mpos      = (const int*)  d_in[3];

    float* out      = (float*)d_out;
    float* cls_out  = out;                                      // [16384]
    float* acc_out  = out + N_INS;                              // [1]
    float* mem_out  = out + N_INS + 1;                          // [81*10*2048]
    float* pos_out  = mem_out + (size_t)N_CLS * BANK * INS_DIM; // [81]

    // scratch inside new_mem output region (consumed before update overwrites):
    //   mean  [0, 165888) f32
    //   base  [165888, 166050) as f64 (byte 663552, 8-aligned)
    //   bestS [166050, 231586) as f64[2][16384] (byte 664200, 8-aligned)
    //   bestC [231586, 264354) as i32[2][16384]
    float*  mean_scr = mem_out;
    double* base_scr = (double*)(mem_out + (size_t)N_CLS * INS_DIM);
    double* bestS    = (double*)(mem_out + 166050);
    int*    bestC    = (int*)   (mem_out + 231586);

    hipMemsetAsync(acc_out, 0, sizeof(float), stream);
    hipLaunchKernelGGL(prep_kernel, dim3(N_CLS), dim3(256), 0, stream,
                       memory, mean_scr, base_scr);
    hipLaunchKernelGGL(classify_kernel, dim3(512), dim3(256), 0, stream,
                       instances, mean_scr, base_scr, bestS, bestC);
    hipLaunchKernelGGL(combine_kernel, dim3(N_INS / 256), dim3(256), 0, stream,
                       bestS, bestC, labels, cls_out, acc_out);
    hipLaunchKernelGGL(update_kernel, dim3(N_CLS), dim3(64), 0, stream,
                       instances, labels, memory, mpos, mem_out, pos_out);
}

// Round 5
// 1008.586 us; speedup vs baseline: 1.4821x; 1.4821x over previous
//
#include <hip/hip_runtime.h>
#include <cstdint>
#include <cstddef>

#define N_INS    16384
#define INS_DIM  2048
#define N_CLS    81
#define BANK     10
#define UCAP     512

// ---------------------------------------------------------------------------
// Kernel 1: per-class mean over bank + ||mean||^2 (f64)
// ---------------------------------------------------------------------------
__global__ __launch_bounds__(256)
void prep_kernel(const float* __restrict__ memory,
                 float*  __restrict__ mean_out,   // [81][2048]
                 double* __restrict__ base_out)   // [81]
{
    const int c = blockIdx.x;
    const int t = threadIdx.x;
    double nrm = 0.0;
    #pragma unroll
    for (int rep = 0; rep < 2; ++rep) {
        const int d4 = (t + rep * 256) * 4;
        float sx = 0.f, sy = 0.f, sz = 0.f, sw = 0.f;
        #pragma unroll
        for (int b = 0; b < BANK; ++b) {
            const float4 v = *(const float4*)(memory + ((size_t)(c * BANK + b)) * INS_DIM + d4);
            sx += v.x; sy += v.y; sz += v.z; sw += v.w;
        }
        sx /= 10.0f; sy /= 10.0f; sz /= 10.0f; sw /= 10.0f;
        *(float4*)(mean_out + (size_t)c * INS_DIM + d4) = make_float4(sx, sy, sz, sw);
        nrm += (double)sx * sx + (double)sy * sy + (double)sz * sz + (double)sw * sw;
    }
    #pragma unroll
    for (int o = 32; o >= 1; o >>= 1) nrm += __shfl_xor(nrm, o, 64);
    __shared__ double sred[4];
    const int w = t >> 6, lane = t & 63;
    if (lane == 0) sred[w] = nrm;
    __syncthreads();
    if (t == 0) base_out[c] = sred[0] + sred[1] + sred[2] + sred[3];
}

// ---------------------------------------------------------------------------
// Kernel 2: classification. 256 blocks x 1024 thr (16 waves/CU, 4/SIMD).
// Block = 64 instances (lane = instance). Wave w owns 6 classes (96 padded).
// B rows wave-uniform -> scalar loads (no LDS, no VGPR cost). A tile 64x64
// in LDS, XOR-swizzled by (l>>3) -> conflict-free ds_read_b128, dbuf,
// one barrier per ktile, prefetch issued after the barrier.
// ---------------------------------------------------------------------------
__global__ __launch_bounds__(1024, 4)
void classify_kernel(const float* __restrict__ instances,
                     const int*   __restrict__ labels,
                     const float* __restrict__ mean_in,   // [81][2048]
                     const double* __restrict__ base_in,  // [81]
                     float* __restrict__ cls_out,         // [16384]
                     float* __restrict__ acc_out)         // [1]
{
    __shared__ float  sA[2][64 * 64];   // 32 KB
    __shared__ double sS[64 * 16];      // 8 KB
    __shared__ int    sC[64 * 16];      // 4 KB

    const int t = threadIdx.x;
    const int l = t & 63;
    const int w = __builtin_amdgcn_readfirstlane(t >> 6);   // 0..15 uniform
    const int i0 = blockIdx.x * 64;

    // staging: thread t -> instance si, chunk sj (16 float4 chunks per row)
    const int si = t >> 4, sj = t & 15;
    const float* gsrc = instances + (size_t)(i0 + si) * INS_DIM + sj * 4;
    const int sdst = si * 64 + ((sj ^ (si >> 3)) & 15) * 4;

    const float* bptr[6];
    #pragma unroll
    for (int cc = 0; cc < 6; ++cc) {
        int row = w * 6 + cc; if (row > N_CLS - 1) row = N_CLS - 1;
        bptr[cc] = mean_in + (size_t)row * INS_DIM;
    }

    double dacc[6];
    #pragma unroll
    for (int cc = 0; cc < 6; ++cc) dacc[cc] = 0.0;

    float4 g = *(const float4*)gsrc;

    for (int kt = 0; kt < 32; ++kt) {     // BK = 64
        const int pb = kt & 1;
        *(float4*)&sA[pb][sdst] = g;
        __syncthreads();
        if (kt < 31) g = *(const float4*)(gsrc + (size_t)(kt + 1) * 64);

        #pragma unroll
        for (int h = 0; h < 2; ++h) {
            float a[32];
            #pragma unroll
            for (int j = 0; j < 8; ++j) {
                const int ch = h * 8 + j;
                *(float4*)&a[j * 4] =
                    *(const float4*)&sA[pb][l * 64 + ((ch ^ (l >> 3)) & 15) * 4];
            }
            #pragma unroll
            for (int cc = 0; cc < 6; ++cc) {
                const float* bp = bptr[cc] + kt * 64 + h * 32;   // uniform
                float p0 = 0.f, p1 = 0.f;
                #pragma unroll
                for (int k = 0; k < 16; ++k) p0 = fmaf(a[k], bp[k], p0);
                #pragma unroll
                for (int k = 16; k < 32; ++k) p1 = fmaf(a[k], bp[k], p1);
                dacc[cc] += (double)p0 + (double)p1;
            }
        }
    }

    // per-wave argmin over its 6 classes (ascending -> first-min)
    double best = 1e300; int bc = 1 << 30;
    #pragma unroll
    for (int cc = 0; cc < 6; ++cc) {
        const int cg = w * 6 + cc;
        if (cg < N_CLS) {
            const double sc = base_in[cg] - 2.0 * dacc[cc];
            if (sc < best) { best = sc; bc = cg; }
        }
    }
    sS[l * 16 + w] = best;
    sC[l * 16 + w] = bc;
    __syncthreads();

    if (t < 64) {
        double b = sS[t * 16]; int cbest = sC[t * 16];
        #pragma unroll
        for (int gq = 1; gq < 16; ++gq) {
            const double v = sS[t * 16 + gq];
            if (v < b) { b = v; cbest = sC[t * 16 + gq]; }  // waves ascend in class
        }
        const int gi = i0 + t;
        cls_out[gi] = (float)cbest;
        const unsigned long long mb = __ballot(cbest == labels[gi]);
        if (t == 0) atomicAdd(acc_out, (float)__popcll(mb) * (1.0f / 16384.0f));
    }
}

// ---------------------------------------------------------------------------
// Kernel 3: sequential per-class update. ONE WAVE per class, zero barriers.
// Bank lives in LDS (80 KB -- no spill possible). Lookahead: while deciding
// step i, issue the LDS reads + dots for step i+1 against the PRE-insert
// bank; the single changed slot is fixed up with the x_i.x_{i+1} correction.
// Scores: argmax ||m_s - x||^2 == argmax (||m_s||^2 - 2 m_s.x).
// ---------------------------------------------------------------------------

#define USTEP(XC, XN, II)                                                     \
  do {                                                                        \
    /* A) dots for step II+1: bank(LDS) . XN ; also XC.XN and XN.XN */        \
    double nx[12];                                                            \
    _Pragma("unroll")                                                         \
    for (int s_ = 0; s_ < 10; ++s_) {                                         \
      float p0_ = 0.f, p1_ = 0.f;                                             \
      _Pragma("unroll")                                                       \
      for (int j_ = 0; j_ < 4; ++j_) {                                        \
        const float4 bv_ = *(const float4*)&s_bank[s_ * INS_DIM + j_ * 256 + l * 4]; \
        p0_ = fmaf(bv_.x, (XN)[j_].x, p0_); p0_ = fmaf(bv_.y, (XN)[j_].y, p0_); \
        p0_ = fmaf(bv_.z, (XN)[j_].z, p0_); p0_ = fmaf(bv_.w, (XN)[j_].w, p0_); \
      }                                                                       \
      _Pragma("unroll")                                                       \
      for (int j_ = 4; j_ < 8; ++j_) {                                        \
        const float4 bv_ = *(const float4*)&s_bank[s_ * INS_DIM + j_ * 256 + l * 4]; \
        p1_ = fmaf(bv_.x, (XN)[j_].x, p1_); p1_ = fmaf(bv_.y, (XN)[j_].y, p1_); \
        p1_ = fmaf(bv_.z, (XN)[j_].z, p1_); p1_ = fmaf(bv_.w, (XN)[j_].w, p1_); \
      }                                                                       \
      nx[s_] = (double)p0_ + (double)p1_;                                     \
    }                                                                         \
    { float p0_ = 0.f, p1_ = 0.f, q0_ = 0.f, q1_ = 0.f;                       \
      _Pragma("unroll")                                                       \
      for (int j_ = 0; j_ < 4; ++j_) {                                        \
        p0_ = fmaf((XC)[j_].x, (XN)[j_].x, p0_); p0_ = fmaf((XC)[j_].y, (XN)[j_].y, p0_); \
        p0_ = fmaf((XC)[j_].z, (XN)[j_].z, p0_); p0_ = fmaf((XC)[j_].w, (XN)[j_].w, p0_); \
        q0_ = fmaf((XN)[j_].x, (XN)[j_].x, q0_); q0_ = fmaf((XN)[j_].y, (XN)[j_].y, q0_); \
        q0_ = fmaf((XN)[j_].z, (XN)[j_].z, q0_); q0_ = fmaf((XN)[j_].w, (XN)[j_].w, q0_); \
      }                                                                       \
      _Pragma("unroll")                                                       \
      for (int j_ = 4; j_ < 8; ++j_) {                                        \
        p1_ = fmaf((XC)[j_].x, (XN)[j_].x, p1_); p1_ = fmaf((XC)[j_].y, (XN)[j_].y, p1_); \
        p1_ = fmaf((XC)[j_].z, (XN)[j_].z, p1_); p1_ = fmaf((XC)[j_].w, (XN)[j_].w, p1_); \
        q1_ = fmaf((XN)[j_].x, (XN)[j_].x, q1_); q1_ = fmaf((XN)[j_].y, (XN)[j_].y, q1_); \
        q1_ = fmaf((XN)[j_].z, (XN)[j_].z, q1_); q1_ = fmaf((XN)[j_].w, (XN)[j_].w, q1_); \
      }                                                                       \
      nx[10] = (double)p0_ + (double)p1_;                                     \
      nx[11] = (double)q0_ + (double)q1_; }                                   \
    /* B) decide step II from previous butterfly (Dcur/ccur/xxcur/wprev) */   \
    int widx_;                                                                \
    if (p < BANK) {                                                           \
      widx_ = p;                                                              \
    } else {                                                                  \
      double bs_ = nrm[0] - 2.0 * ((0 == wprev) ? ccur : Dcur[0]);            \
      widx_ = 0;                                                              \
      _Pragma("unroll")                                                       \
      for (int s_ = 1; s_ < 10; ++s_) {                                       \
        const double v_ = nrm[s_] - 2.0 * ((s_ == wprev) ? ccur : Dcur[s_]);  \
        if (v_ > bs_) { bs_ = v_; widx_ = s_; }                               \
      }                                                                       \
    }                                                                         \
    const int sw_ = __builtin_amdgcn_readfirstlane(widx_);                    \
    _Pragma("unroll")                                                         \
    for (int s_ = 0; s_ < 10; ++s_) if (sw_ == s_) nrm[s_] = xxcur;           \
    if (p < BANK) ++p;                                                        \
    /* C) insert XC into LDS slot sw_ (after A's reads: program order) */     \
    { float* dst_ = &s_bank[sw_ * INS_DIM + l * 4];                           \
      _Pragma("unroll")                                                       \
      for (int j_ = 0; j_ < 8; ++j_) *(float4*)(dst_ + j_ * 256) = (XC)[j_]; }\
    /* D) butterfly the 12 new values */                                      \
    _Pragma("unroll")                                                         \
    for (int o_ = 32; o_ >= 1; o_ >>= 1) {                                    \
      _Pragma("unroll")                                                       \
      for (int v_ = 0; v_ < 12; ++v_) nx[v_] += __shfl_xor(nx[v_], o_, 64);   \
    }                                                                         \
    /* E) rotate state */                                                     \
    wprev = widx_;                                                            \
    _Pragma("unroll")                                                         \
    for (int v_ = 0; v_ < 10; ++v_) Dcur[v_] = nx[v_];                        \
    ccur = nx[10]; xxcur = nx[11];                                            \
    /* F) prefetch x_{II+2} into XC (XC free after insert) */                 \
    { const int nid_ = s_list[((II) + 2 < cnt) ? (II) + 2 : (cnt - 1)];       \
      const float* pp_ = instances + (size_t)nid_ * INS_DIM + l * 4;          \
      _Pragma("unroll")                                                       \
      for (int j_ = 0; j_ < 8; ++j_) (XC)[j_] = *(const float4*)(pp_ + j_ * 256); } \
  } while (0)

__global__ __launch_bounds__(64, 1)
void update_kernel(const float* __restrict__ instances,
                   const int*   __restrict__ labels,
                   const float* __restrict__ memory,
                   const int*   __restrict__ memory_pos,
                   float* __restrict__ mem_out,   // [81][10][2048]
                   float* __restrict__ pos_out)   // [81]
{
    __shared__ float s_bank[BANK * INS_DIM];   // 80 KB
    __shared__ int   s_list[UCAP];             // 2 KB

    const int c = blockIdx.x;
    const int l = threadIdx.x;
    const unsigned long long below = (1ull << l) - 1ull;

    // ---- Phase 1: stable compaction of indices with label == c
    int cnt = 0;
    {
        int4 lb[2][8];
        #pragma unroll
        for (int u = 0; u < 8; ++u) lb[0][u] = ((const int4*)labels)[u * 64 + l];
        for (int bt = 0; bt < 8; ++bt) {
            const int cur = bt & 1;
            if (bt < 7) {
                #pragma unroll
                for (int u = 0; u < 8; ++u)
                    lb[cur ^ 1][u] = ((const int4*)labels)[((bt + 1) * 8 + u) * 64 + l];
            }
            #pragma unroll
            for (int u = 0; u < 8; ++u) {
                const int4 lv = lb[cur][u];
                const int base = (bt * 8 + u) * 256 + 4 * l;
                const bool q0 = (lv.x == c), q1 = (lv.y == c), q2 = (lv.z == c), q3 = (lv.w == c);
                const unsigned long long b0 = __ballot(q0), b1 = __ballot(q1),
                                         b2 = __ballot(q2), b3 = __ballot(q3);
                int pos = cnt + (int)(__popcll(b0 & below) + __popcll(b1 & below) +
                                      __popcll(b2 & below) + __popcll(b3 & below));
                if (q0) { if (pos < UCAP) s_list[pos] = base + 0; ++pos; }
                if (q1) { if (pos < UCAP) s_list[pos] = base + 1; ++pos; }
                if (q2) { if (pos < UCAP) s_list[pos] = base + 2; ++pos; }
                if (q3) { if (pos < UCAP) s_list[pos] = base + 3; ++pos; }
                cnt += (int)(__popcll(b0) + __popcll(b1) + __popcll(b2) + __popcll(b3));
            }
        }
        if (cnt > UCAP) cnt = UCAP;
    }

    // ---- Phase 2: x0/x1 loads; bank global->LDS while computing nrm + D0
    float4 xa[8], xb[8];
    #pragma unroll
    for (int j = 0; j < 8; ++j) { xa[j] = make_float4(0,0,0,0); xb[j] = make_float4(0,0,0,0); }
    if (cnt > 0) {
        const float* p0 = instances + (size_t)s_list[0] * INS_DIM + l * 4;
        #pragma unroll
        for (int j = 0; j < 8; ++j) xa[j] = *(const float4*)(p0 + j * 256);
        const float* p1 = instances + (size_t)s_list[(cnt > 1) ? 1 : 0] * INS_DIM + l * 4;
        #pragma unroll
        for (int j = 0; j < 8; ++j) xb[j] = *(const float4*)(p1 + j * 256);
    }

    double nrm[10], Dcur[10], ccur = 0.0, xxcur = 0.0;
    {
        double red[21];
        #pragma unroll
        for (int s = 0; s < 10; ++s) {
            float n0 = 0.f, n1 = 0.f, d0 = 0.f, d1 = 0.f;
            #pragma unroll
            for (int j = 0; j < 4; ++j) {
                const float4 v = *(const float4*)(memory + ((size_t)(c * BANK + s)) * INS_DIM + j * 256 + l * 4);
                *(float4*)&s_bank[s * INS_DIM + j * 256 + l * 4] = v;
                n0 = fmaf(v.x, v.x, n0); n0 = fmaf(v.y, v.y, n0);
                n0 = fmaf(v.z, v.z, n0); n0 = fmaf(v.w, v.w, n0);
                d0 = fmaf(v.x, xa[j].x, d0); d0 = fmaf(v.y, xa[j].y, d0);
                d0 = fmaf(v.z, xa[j].z, d0); d0 = fmaf(v.w, xa[j].w, d0);
            }
            #pragma unroll
            for (int j = 4; j < 8; ++j) {
                const float4 v = *(const float4*)(memory + ((size_t)(c * BANK + s)) * INS_DIM + j * 256 + l * 4);
                *(float4*)&s_bank[s * INS_DIM + j * 256 + l * 4] = v;
                n1 = fmaf(v.x, v.x, n1); n1 = fmaf(v.y, v.y, n1);
                n1 = fmaf(v.z, v.z, n1); n1 = fmaf(v.w, v.w, n1);
                d1 = fmaf(v.x, xa[j].x, d1); d1 = fmaf(v.y, xa[j].y, d1);
                d1 = fmaf(v.z, xa[j].z, d1); d1 = fmaf(v.w, xa[j].w, d1);
            }
            red[s]      = (double)n0 + (double)n1;
            red[10 + s] = (double)d0 + (double)d1;
        }
        { float q0 = 0.f, q1 = 0.f;
          #pragma unroll
          for (int j = 0; j < 4; ++j) {
              q0 = fmaf(xa[j].x, xa[j].x, q0); q0 = fmaf(xa[j].y, xa[j].y, q0);
              q0 = fmaf(xa[j].z, xa[j].z, q0); q0 = fmaf(xa[j].w, xa[j].w, q0);
          }
          #pragma unroll
          for (int j = 4; j < 8; ++j) {
              q1 = fmaf(xa[j].x, xa[j].x, q1); q1 = fmaf(xa[j].y, xa[j].y, q1);
              q1 = fmaf(xa[j].z, xa[j].z, q1); q1 = fmaf(xa[j].w, xa[j].w, q1);
          }
          red[20] = (double)q0 + (double)q1; }
        #pragma unroll
        for (int o = 32; o >= 1; o >>= 1)
            #pragma unroll
            for (int v = 0; v < 21; ++v) red[v] += __shfl_xor(red[v], o, 64);
        #pragma unroll
        for (int s = 0; s < 10; ++s) { nrm[s] = red[s]; Dcur[s] = red[10 + s]; }
        xxcur = red[20];
    }

    int p = memory_pos[c];
    int wprev = -1;

    // ---- Phase 3: lookahead scan (no barriers, bank in LDS)
    int ii = 0;
    while (ii < cnt) {
        USTEP(xa, xb, ii); ++ii;
        if (ii >= cnt) break;
        USTEP(xb, xa, ii); ++ii;
    }

    // ---- Phase 4: write bank + pos
    #pragma unroll
    for (int s = 0; s < 10; ++s)
        #pragma unroll
        for (int j = 0; j < 8; ++j)
            *(float4*)(mem_out + ((size_t)(c * BANK + s)) * INS_DIM + j * 256 + l * 4) =
                *(const float4*)&s_bank[s * INS_DIM + j * 256 + l * 4];
    if (l == 0) pos_out[c] = (float)p;
}

// ---------------------------------------------------------------------------
extern "C" void kernel_launch(void* const* d_in, const int* in_sizes, int n_in,
                              void* d_out, int out_size, void* d_ws, size_t ws_size,
                              hipStream_t stream)
{
    const float* instances = (const float*)d_in[0];
    const int*   labels    = (const int*)  d_in[1];
    const float* memory    = (const float*)d_in[2];
    const int*   mpos      = (const int*)  d_in[3];

    float* out      = (float*)d_out;
    float* cls_out  = out;                                      // [16384]
    float* acc_out  = out + N_INS;                              // [1]
    float* mem_out  = out + N_INS + 1;                          // [81*10*2048]
    float* pos_out  = mem_out + (size_t)N_CLS * BANK * INS_DIM; // [81]

    // scratch inside new_mem output region; update_kernel overwrites it last.
    // base at odd float offset 165889 so its byte address is 8-aligned.
    float*  mean_scr = mem_out;                                 // [81*2048]
    double* base_scr = (double*)(mem_out + (size_t)N_CLS * INS_DIM + 1);

    hipMemsetAsync(acc_out, 0, sizeof(float), stream);
    hipLaunchKernelGGL(prep_kernel, dim3(N_CLS), dim3(256), 0, stream,
                       memory, mean_scr, base_scr);
    hipLaunchKernelGGL(classify_kernel, dim3(N_INS / 64), dim3(1024), 0, stream,
                       instances, labels, mean_scr, base_scr, cls_out, acc_out);
    hipLaunchKernelGGL(update_kernel, dim3(N_CLS), dim3(64), 0, stream,
                       instances, labels, memory, mpos, mem_out, pos_out);
}